// Round 16
// baseline (40.783 us; speedup 1.0000x reference)
//
#include <hip/hip_runtime.h>

#define NRAYS 8192
#define NSAMP 173
#define LASTI 172
#define NBLK  (NRAYS / 4)

__device__ __forceinline__ float RL(float x, int u) {
    return __int_as_float(__builtin_amdgcn_readlane(__float_as_int(x), u));
}

// DPP helper: result = (lane enabled by masks && src in range) ? src[dpp] : old
template <int CTRL, int RM, bool BC>
__device__ __forceinline__ float updpp(float old, float x) {
    return __int_as_float(__builtin_amdgcn_update_dpp(
        __float_as_int(old), __float_as_int(x), CTRL, RM, 0xf, BC));
}

// wave64 inclusive add-scan
__device__ __forceinline__ float scan_add64(float x) {
    x += updpp<0x111, 0xf, true>(0.f, x);
    x += updpp<0x112, 0xf, true>(0.f, x);
    x += updpp<0x114, 0xf, true>(0.f, x);
    x += updpp<0x118, 0xf, true>(0.f, x);
    x += updpp<0x142, 0xa, true>(0.f, x);
    x += updpp<0x143, 0xc, true>(0.f, x);
    return x;
}

// wave64 inclusive mul-scan
__device__ __forceinline__ float scan_mul64(float x) {
    x *= updpp<0x111, 0xf, false>(1.f, x);
    x *= updpp<0x112, 0xf, false>(1.f, x);
    x *= updpp<0x114, 0xf, false>(1.f, x);
    x *= updpp<0x118, 0xf, false>(1.f, x);
    x *= updpp<0x142, 0xa, false>(1.f, x);
    x *= updpp<0x143, 0xc, false>(1.f, x);
    return x;
}

__device__ __forceinline__ float wave_sum64(float v) {
    return RL(scan_add64(v), 63);
}

__device__ __forceinline__ float softplus_f(float x) {
    if (x > 15.f) return x;
    return __logf(1.f + __expf(x));
}
__device__ __forceinline__ float sigmoid_f(float x) {
    return 1.f / (1.f + __expf(-x));
}

__launch_bounds__(256, 4)
__global__ void render_kernel(
    const float* __restrict__ rays,
    const float* __restrict__ Wd1, const float* __restrict__ bd1,
    const float* __restrict__ Wd2, const float* __restrict__ bd2,
    const float* __restrict__ Wapp, const float* __restrict__ Wa1,
    const float* __restrict__ ba1, const float* __restrict__ Wa2,
    const float* __restrict__ ba2, const float* __restrict__ Wsf,
    const float* __restrict__ Wsm, const float* __restrict__ bsm,
    const float* __restrict__ Wi,
    const int* __restrict__ whitebg_p,
    float* __restrict__ out,
    float* __restrict__ wsdist)
{
    // density weights in LDS (LDS pipe); appearance weights lane-distributed in
    // VGPRs, broadcast via readlane (VALU pipe) -- balances the two pipes.
    __shared__ float4 qd4[64];   // Wd1 cols + bd1
    __shared__ float  wd2s[64];  // Wd2
    __shared__ float  wscs[60];  // (Wsf @ Wsm)[m*20+s]
    __shared__ float  bsmS[20];

    const int t = threadIdx.x;
    const int wid = t >> 6, lane = t & 63;
    const int r = blockIdx.x * 4 + wid;

    // ---- preamble ----
    if (t < 64) {
        qd4[t] = make_float4(Wd1[t], Wd1[64 + t], Wd1[128 + t], bd1[t]);
        wd2s[t] = Wd2[t];
    } else if (t >= 192) {
        for (int job = t - 192; job < 80; job += 64) {
            if (job < 60) {
                int m = job / 20, s = job % 20;
                float a = 0.f;
                for (int k = 0; k < 32; ++k) a = fmaf(Wsf[m * 32 + k], Wsm[k * 20 + s], a);
                wscs[job] = a;
            } else {
                bsmS[job - 60] = bsm[job - 60];
            }
        }
    }

    // ray (wave-uniform)
    const float o0 = rays[r * 6 + 0], o1 = rays[r * 6 + 1], o2 = rays[r * 6 + 2];
    const float d0 = rays[r * 6 + 3], d1 = rays[r * 6 + 4], d2 = rays[r * 6 + 5];

    // per-lane appearance constants for unit == lane (parallel fold, no LDS dep)
    float wc0, wc1, wc2, wb0, wb1, wb2, dcr;
    {
        float s0 = 0.f, s1 = 0.f, s2 = 0.f;
        for (int j = 0; j < 27; ++j) {
            float w = Wa1[j * 64 + lane];     // coalesced
            s0 = fmaf(Wapp[j], w, s0);        // uniform -> scalar loads
            s1 = fmaf(Wapp[27 + j], w, s1);
            s2 = fmaf(Wapp[54 + j], w, s2);
        }
        wc0 = s0; wc1 = s1; wc2 = s2;
        wb0 = Wa2[3 * lane];
        wb1 = Wa2[3 * lane + 1];
        wb2 = Wa2[3 * lane + 2];
        float b = ba1[lane];
        b = fmaf(d0, Wa1[27 * 64 + lane], b);
        b = fmaf(d1, Wa1[28 * 64 + lane], b);
        b = fmaf(d2, Wa1[29 * 64 + lane], b);
        dcr = b;
    }

    // t_min -- replicate numpy f32 rounding exactly (knife-edge: sample 0 on box face)
    float tm;
    {
        float v0 = (d0 == 0.f) ? 1e-6f : d0;
        float v1 = (d1 == 0.f) ? 1e-6f : d1;
        float v2 = (d2 == 0.f) ? 1e-6f : d2;
        float a0 = __fdiv_rn(__fsub_rn(1.5f, o0), v0), b0 = __fdiv_rn(__fsub_rn(-1.5f, o0), v0);
        float a1 = __fdiv_rn(__fsub_rn(1.5f, o1), v1), b1 = __fdiv_rn(__fsub_rn(-1.5f, o1), v1);
        float a2 = __fdiv_rn(__fsub_rn(1.5f, o2), v2), b2 = __fdiv_rn(__fsub_rn(-1.5f, o2), v2);
        float m0 = fminf(a0, b0), m1 = fminf(a1, b1), m2 = fminf(a2, b2);
        tm = fmaxf(fmaxf(m0, m1), m2);
        tm = fminf(fmaxf(tm, 0.05f), 6.0f);
    }

    const float bd2c = bd2[0];
    const float ba2c0 = ba2[0], ba2c1 = ba2[1], ba2c2 = ba2[2];

    __syncthreads();

    const float STEPF = (float)(3.0 / 299.001 * 3.0);
    const float zlast2 = __fadd_rn(tm, __fmul_rn(171.f, STEPF));

    float aR0 = 0.f, aR1 = 0.f, aR2 = 0.f;
    float aS0 = 0.f, aS1 = 0.f, aS2 = 0.f;
    float aSw = 0.f;
    float aD = 0.f, aLu = 0.f, aLb = 0.f;
    float Tc = 1.f, Wcar = 0.f, WMc = 0.f;

    // ---- 3 chunks of 64 samples; wave-uniform early exit (T collapses ~sample 30) ----
    for (int c = 0; c < 3; ++c) {
        int i = (c << 6) + lane;
        bool valid = i < NSAMP;
        float z = __fadd_rn(tm, __fmul_rn((float)i, STEPF));
        float x0 = __fadd_rn(o0, __fmul_rn(d0, z));
        float x1 = __fadd_rn(o1, __fmul_rn(d1, z));
        float x2 = __fadd_rn(o2, __fmul_rn(d2, z));
        bool inbox = valid && (x0 >= -1.5f) && (x0 <= 1.5f) && (x1 >= -1.5f) && (x1 <= 1.5f) &&
                     (x2 >= -1.5f) && (x2 <= 1.5f);
        if (__ballot(inbox) == 0ull) break;  // in-box span is contiguous from sample 0

        float xn0 = x0 * (2.f / 3.f), xn1 = x1 * (2.f / 3.f), xn2 = x2 * (2.f / 3.f);

        // density MLP (LDS broadcast weights -- the only LDS consumer in the loop)
        float sp = bd2c;
#pragma unroll 8
        for (int u = 0; u < 64; ++u) {
            float4 q = qd4[u];
            float h = fmaf(xn0, q.x, fmaf(xn1, q.y, fmaf(xn2, q.z, q.w)));
            sp = fmaf(fmaxf(h, 0.f), wd2s[u], sp);
        }
        float sigma = inbox ? softplus_f(sp) : 0.f;

        float znext = __fadd_rn(tm, __fmul_rn((float)(i + 1), STEPF));
        float dist = (i < LASTI) ? __fsub_rn(znext, z) : 0.f;
        float alpha = 1.f - __expf(-sigma * dist * 25.f);
        float f = 1.f - alpha + 1e-10f;

        // DPP product scan
        float p = scan_mul64(f);
        float pex = updpp<0x138, 0xf, false>(1.f, p);  // wave_shr1, lane0 -> 1
        float T = Tc * pex;
        float w = alpha * T;

        float mid = (i < LASTI) ? 0.5f * __fadd_rn(z, znext) : zlast2;
        float wm = w * mid;

        // DPP sum scans
        float sw = scan_add64(w);
        float swm = scan_add64(wm);
        float wex = updpp<0x138, 0xf, true>(0.f, sw);
        float wmex = updpp<0x138, 0xf, true>(0.f, swm);

        aLb += wm * (Wcar + wex) - w * (WMc + wmex);
        aLu = fmaf(dist * w, w, aLu);
        aD = fmaf(w, z, aD);

        Tc *= RL(p, 63);
        Wcar += RL(sw, 63);
        WMc += RL(swm, 63);

        // appearance (only where w > W_THRES): weights via readlane (VALU pipe)
        float wapp = (w > 1e-4f) ? w : 0.f;
        if (__ballot(wapp > 0.f) != 0ull) {
            float c0 = 0.f, c1 = 0.f, c2 = 0.f;
#pragma unroll 8
            for (int u = 0; u < 64; ++u) {
                float a0 = RL(wc0, u), a1 = RL(wc1, u), a2 = RL(wc2, u);
                float b0 = RL(wb0, u), b1 = RL(wb1, u), b2 = RL(wb2, u);
                float dcu = RL(dcr, u);
                float h = fmaf(xn0, a0, fmaf(xn1, a1, fmaf(xn2, a2, dcu)));
                h = fmaxf(h, 0.f);
                c0 = fmaf(h, b0, c0);
                c1 = fmaf(h, b1, c1);
                c2 = fmaf(h, b2, c2);
            }
            aR0 = fmaf(wapp, sigmoid_f(c0 + ba2c0), aR0);
            aR1 = fmaf(wapp, sigmoid_f(c1 + ba2c1), aR1);
            aR2 = fmaf(wapp, sigmoid_f(c2 + ba2c2), aR2);
            aS0 = fmaf(wapp, xn0, aS0);
            aS1 = fmaf(wapp, xn1, aS1);
            aS2 = fmaf(wapp, xn2, aS2);
            aSw += wapp;
        }

        if (Tc < 1e-8f) break;  // all later weights < 1e-8 << W_THRES
    }

    // wave reductions (DPP scan + readlane)
    aR0 = wave_sum64(aR0); aR1 = wave_sum64(aR1); aR2 = wave_sum64(aR2);
    aS0 = wave_sum64(aS0); aS1 = wave_sum64(aS1); aS2 = wave_sum64(aS2);
    aSw = wave_sum64(aSw);
    aD = wave_sum64(aD);
    aLu = wave_sum64(aLu);
    aLb = wave_sum64(aLb);

    float opac = Wcar;
    int wb = *whitebg_p;
    float bg = wb ? (1.f - opac) : 0.f;

    float* out_rgb = out;
    float* out_sem = out + 24576;
    float* out_inst = out + 188416;
    float* out_dep = out + 319488;

    if (lane < 3) {
        float rv = (lane == 0 ? aR0 : (lane == 1 ? aR1 : aR2)) + bg;
        rv = fminf(fmaxf(rv, 0.f), 1.f);
        out_rgb[r * 3 + lane] = rv;
    }
    if (lane < 20) {
        float sv = aS0 * wscs[lane] + aS1 * wscs[20 + lane] + aS2 * wscs[40 + lane] +
                   aSw * bsmS[lane];
        out_sem[r * 20 + lane] = sv;
    }
    if (lane < 16) {
        float iv = aS0 * Wi[lane] + aS1 * Wi[16 + lane] + aS2 * Wi[32 + lane];
        out_inst[r * 16 + lane] = iv;
    }
    if (lane == 0) {
        out_dep[r] = aD;
        wsdist[r] = aLu * (1.f / 3.f) + 2.f * aLb;
    }
}

__global__ void reduce_dist_kernel(const float* __restrict__ ws, float* __restrict__ out) {
    __shared__ float sm[256];
    int t = threadIdx.x;
    float a = 0.f;
    const float4* w4 = (const float4*)ws;
    for (int i = t; i < NRAYS / 4; i += 256) {
        float4 v = w4[i];
        a += (v.x + v.y) + (v.z + v.w);
    }
    sm[t] = a;
    __syncthreads();
    for (int st = 128; st > 0; st >>= 1) {
        if (t < st) sm[t] += sm[t + st];
        __syncthreads();
    }
    if (t == 0) out[0] = sm[0] * (1.f / (float)NRAYS);
}

extern "C" void kernel_launch(void* const* d_in, const int* in_sizes, int n_in,
                              void* d_out, int out_size, void* d_ws, size_t ws_size,
                              hipStream_t stream) {
    const float* rays = (const float*)d_in[0];
    const float* Wd1  = (const float*)d_in[1];
    const float* bd1  = (const float*)d_in[2];
    const float* Wd2  = (const float*)d_in[3];
    const float* bd2  = (const float*)d_in[4];
    const float* Wapp = (const float*)d_in[5];
    const float* Wa1  = (const float*)d_in[6];
    const float* ba1  = (const float*)d_in[7];
    const float* Wa2  = (const float*)d_in[8];
    const float* ba2  = (const float*)d_in[9];
    const float* Wsf  = (const float*)d_in[10];
    const float* Wsm  = (const float*)d_in[11];
    const float* bsm  = (const float*)d_in[12];
    const float* Wi   = (const float*)d_in[13];
    const int* wb     = (const int*)d_in[15];

    float* out = (float*)d_out;
    float* wsd = (float*)d_ws;   // 8192 f32 per-ray dist values

    render_kernel<<<NBLK, 256, 0, stream>>>(rays, Wd1, bd1, Wd2, bd2, Wapp, Wa1, ba1,
                                            Wa2, ba2, Wsf, Wsm, bsm, Wi, wb, out, wsd);
    reduce_dist_kernel<<<1, 256, 0, stream>>>(wsd, out + 327680);
}

// Round 17
// 34.288 us; speedup vs baseline: 1.1894x; 1.1894x over previous
//
#include <hip/hip_runtime.h>

#define NRAYS 8192
#define NSAMP 173
#define LASTI 172
#define RAYS_PER_WAVE 4
#define NBLK (NRAYS / (4 * RAYS_PER_WAVE))   // 512 blocks, 4 waves each

__device__ __forceinline__ float RL(float x, int u) {
    return __int_as_float(__builtin_amdgcn_readlane(__float_as_int(x), u));
}

// DPP helper: result = (lane enabled by masks && src in range) ? src[dpp] : old
template <int CTRL, int RM, bool BC>
__device__ __forceinline__ float updpp(float old, float x) {
    return __int_as_float(__builtin_amdgcn_update_dpp(
        __float_as_int(old), __float_as_int(x), CTRL, RM, 0xf, BC));
}

// wave64 inclusive add-scan
__device__ __forceinline__ float scan_add64(float x) {
    x += updpp<0x111, 0xf, true>(0.f, x);
    x += updpp<0x112, 0xf, true>(0.f, x);
    x += updpp<0x114, 0xf, true>(0.f, x);
    x += updpp<0x118, 0xf, true>(0.f, x);
    x += updpp<0x142, 0xa, true>(0.f, x);
    x += updpp<0x143, 0xc, true>(0.f, x);
    return x;
}

// wave64 inclusive mul-scan
__device__ __forceinline__ float scan_mul64(float x) {
    x *= updpp<0x111, 0xf, false>(1.f, x);
    x *= updpp<0x112, 0xf, false>(1.f, x);
    x *= updpp<0x114, 0xf, false>(1.f, x);
    x *= updpp<0x118, 0xf, false>(1.f, x);
    x *= updpp<0x142, 0xa, false>(1.f, x);
    x *= updpp<0x143, 0xc, false>(1.f, x);
    return x;
}

__device__ __forceinline__ float wave_sum64(float v) {
    return RL(scan_add64(v), 63);
}

__device__ __forceinline__ float softplus_f(float x) {
    if (x > 15.f) return x;
    return __logf(1.f + __expf(x));
}
__device__ __forceinline__ float sigmoid_f(float x) {
    return 1.f / (1.f + __expf(-x));
}

__launch_bounds__(256, 2)
__global__ void render_kernel(
    const float* __restrict__ rays,
    const float* __restrict__ Wd1, const float* __restrict__ bd1,
    const float* __restrict__ Wd2, const float* __restrict__ bd2,
    const float* __restrict__ Wapp, const float* __restrict__ Wa1,
    const float* __restrict__ ba1, const float* __restrict__ Wa2,
    const float* __restrict__ ba2, const float* __restrict__ Wsf,
    const float* __restrict__ Wsm, const float* __restrict__ bsm,
    const float* __restrict__ Wi,
    const int* __restrict__ whitebg_p,
    float* __restrict__ out,
    float* __restrict__ wsdist)
{
    // per-block folded weight tables in LDS (broadcast reads, no conflicts)
    __shared__ float4 qd4[64];   // Wd1 cols + bd1
    __shared__ float  wd2s[64];  // Wd2
    __shared__ float4 apAs[64];  // (wac0, wac1, wac2, Wa2[u][0]);  wac = Wapp @ Wa1[:27]
    __shared__ float2 apBs[64];  // (Wa2[u][1], Wa2[u][2])
    __shared__ float  wscs[60];  // (Wsf @ Wsm)[m*20+s]
    __shared__ float  bsmS[20];

    const int t = threadIdx.x;
    const int wid = t >> 6, lane = t & 63;
    const int rbase = (blockIdx.x * 4 + wid) * RAYS_PER_WAVE;

    // ---- preamble: fold tables once per block (amortized over 16 rays) ----
    if (t < 64) {
        qd4[t] = make_float4(Wd1[t], Wd1[64 + t], Wd1[128 + t], bd1[t]);
        wd2s[t] = Wd2[t];
    } else if (t < 128) {
        int u = t - 64;
        apBs[u] = make_float2(Wa2[3 * u + 1], Wa2[3 * u + 2]);
    } else if (t < 192) {
        int u = t - 128;
        float s0 = 0.f, s1 = 0.f, s2 = 0.f;
        for (int j = 0; j < 27; ++j) {
            float w = Wa1[j * 64 + u];
            s0 = fmaf(Wapp[j], w, s0);
            s1 = fmaf(Wapp[27 + j], w, s1);
            s2 = fmaf(Wapp[54 + j], w, s2);
        }
        apAs[u] = make_float4(s0, s1, s2, Wa2[3 * u]);
    } else {
        for (int job = t - 192; job < 80; job += 64) {
            if (job < 60) {
                int m = job / 20, s = job % 20;
                float a = 0.f;
                for (int k = 0; k < 32; ++k) a = fmaf(Wsf[m * 32 + k], Wsm[k * 20 + s], a);
                wscs[job] = a;
            } else {
                bsmS[job - 60] = bsm[job - 60];
            }
        }
    }

    // per-lane dconst ingredients (ray-independent; hoisted out of the ray loop)
    const float wa1d0 = Wa1[27 * 64 + lane];
    const float wa1d1 = Wa1[28 * 64 + lane];
    const float wa1d2 = Wa1[29 * 64 + lane];
    const float ba1l = ba1[lane];

    const float bd2c = bd2[0];
    const float ba2c0 = ba2[0], ba2c1 = ba2[1], ba2c2 = ba2[2];
    const int wb = *whitebg_p;

    __syncthreads();

    const float STEPF = (float)(3.0 / 299.001 * 3.0);

    float* out_rgb = out;
    float* out_sem = out + 24576;
    float* out_inst = out + 188416;
    float* out_dep = out + 319488;

    // ---- 4 rays per wave, sequential (preamble amortized) ----
    for (int rr = 0; rr < RAYS_PER_WAVE; ++rr) {
        const int r = rbase + rr;

        const float o0 = rays[r * 6 + 0], o1 = rays[r * 6 + 1], o2 = rays[r * 6 + 2];
        const float d0 = rays[r * 6 + 3], d1 = rays[r * 6 + 4], d2 = rays[r * 6 + 5];

        // t_min -- replicate numpy f32 rounding exactly (knife-edge: sample 0 on box face)
        float tm;
        {
            float v0 = (d0 == 0.f) ? 1e-6f : d0;
            float v1 = (d1 == 0.f) ? 1e-6f : d1;
            float v2 = (d2 == 0.f) ? 1e-6f : d2;
            float a0 = __fdiv_rn(__fsub_rn(1.5f, o0), v0), b0 = __fdiv_rn(__fsub_rn(-1.5f, o0), v0);
            float a1 = __fdiv_rn(__fsub_rn(1.5f, o1), v1), b1 = __fdiv_rn(__fsub_rn(-1.5f, o1), v1);
            float a2 = __fdiv_rn(__fsub_rn(1.5f, o2), v2), b2 = __fdiv_rn(__fsub_rn(-1.5f, o2), v2);
            float m0 = fminf(a0, b0), m1 = fminf(a1, b1), m2 = fminf(a2, b2);
            tm = fmaxf(fmaxf(m0, m1), m2);
            tm = fminf(fmaxf(tm, 0.05f), 6.0f);
        }

        // per-ray appearance dconst for unit==lane
        float dcr = ba1l;
        dcr = fmaf(d0, wa1d0, dcr);
        dcr = fmaf(d1, wa1d1, dcr);
        dcr = fmaf(d2, wa1d2, dcr);

        const float zlast2 = __fadd_rn(tm, __fmul_rn(171.f, STEPF));

        float aR0 = 0.f, aR1 = 0.f, aR2 = 0.f;
        float aS0 = 0.f, aS1 = 0.f, aS2 = 0.f;
        float aSw = 0.f;
        float aD = 0.f, aLu = 0.f, aLb = 0.f;
        float Tc = 1.f, Wcar = 0.f, WMc = 0.f;

        // ---- 3 chunks of 64 samples; wave-uniform early exit ----
        for (int c = 0; c < 3; ++c) {
            int i = (c << 6) + lane;
            bool valid = i < NSAMP;
            float z = __fadd_rn(tm, __fmul_rn((float)i, STEPF));
            float x0 = __fadd_rn(o0, __fmul_rn(d0, z));
            float x1 = __fadd_rn(o1, __fmul_rn(d1, z));
            float x2 = __fadd_rn(o2, __fmul_rn(d2, z));
            bool inbox = valid && (x0 >= -1.5f) && (x0 <= 1.5f) && (x1 >= -1.5f) && (x1 <= 1.5f) &&
                         (x2 >= -1.5f) && (x2 <= 1.5f);
            if (__ballot(inbox) == 0ull) break;  // in-box span is contiguous from sample 0

            float xn0 = x0 * (2.f / 3.f), xn1 = x1 * (2.f / 3.f), xn2 = x2 * (2.f / 3.f);

            // density MLP (LDS broadcast weights)
            float sp = bd2c;
#pragma unroll 8
            for (int u = 0; u < 64; ++u) {
                float4 q = qd4[u];
                float h = fmaf(xn0, q.x, fmaf(xn1, q.y, fmaf(xn2, q.z, q.w)));
                sp = fmaf(fmaxf(h, 0.f), wd2s[u], sp);
            }
            float sigma = inbox ? softplus_f(sp) : 0.f;

            float znext = __fadd_rn(tm, __fmul_rn((float)(i + 1), STEPF));
            float dist = (i < LASTI) ? __fsub_rn(znext, z) : 0.f;
            float alpha = 1.f - __expf(-sigma * dist * 25.f);
            float f = 1.f - alpha + 1e-10f;

            // DPP product scan
            float p = scan_mul64(f);
            float pex = updpp<0x138, 0xf, false>(1.f, p);  // wave_shr1, lane0 -> 1
            float T = Tc * pex;
            float w = alpha * T;

            float mid = (i < LASTI) ? 0.5f * __fadd_rn(z, znext) : zlast2;
            float wm = w * mid;

            // DPP sum scans
            float sw = scan_add64(w);
            float swm = scan_add64(wm);
            float wex = updpp<0x138, 0xf, true>(0.f, sw);
            float wmex = updpp<0x138, 0xf, true>(0.f, swm);

            aLb += wm * (Wcar + wex) - w * (WMc + wmex);
            aLu = fmaf(dist * w, w, aLu);
            aD = fmaf(w, z, aD);

            Tc *= RL(p, 63);
            Wcar += RL(sw, 63);
            WMc += RL(swm, 63);

            // appearance (only where w > W_THRES)
            float wapp = (w > 1e-4f) ? w : 0.f;
            if (__ballot(wapp > 0.f) != 0ull) {
                float c0 = 0.f, c1 = 0.f, c2 = 0.f;
#pragma unroll 8
                for (int u = 0; u < 64; ++u) {
                    float4 A4 = apAs[u];
                    float2 B2 = apBs[u];
                    float dcu = RL(dcr, u);
                    float h = fmaf(xn0, A4.x, fmaf(xn1, A4.y, fmaf(xn2, A4.z, dcu)));
                    h = fmaxf(h, 0.f);
                    c0 = fmaf(h, A4.w, c0);
                    c1 = fmaf(h, B2.x, c1);
                    c2 = fmaf(h, B2.y, c2);
                }
                aR0 = fmaf(wapp, sigmoid_f(c0 + ba2c0), aR0);
                aR1 = fmaf(wapp, sigmoid_f(c1 + ba2c1), aR1);
                aR2 = fmaf(wapp, sigmoid_f(c2 + ba2c2), aR2);
                aS0 = fmaf(wapp, xn0, aS0);
                aS1 = fmaf(wapp, xn1, aS1);
                aS2 = fmaf(wapp, xn2, aS2);
                aSw += wapp;
            }

            if (Tc < 1e-8f) break;  // all later weights < 1e-8 << W_THRES
        }

        // wave reductions (DPP scan + readlane)
        aR0 = wave_sum64(aR0); aR1 = wave_sum64(aR1); aR2 = wave_sum64(aR2);
        aS0 = wave_sum64(aS0); aS1 = wave_sum64(aS1); aS2 = wave_sum64(aS2);
        aSw = wave_sum64(aSw);
        aD = wave_sum64(aD);
        aLu = wave_sum64(aLu);
        aLb = wave_sum64(aLb);

        float opac = Wcar;
        float bg = wb ? (1.f - opac) : 0.f;

        if (lane < 3) {
            float rv = (lane == 0 ? aR0 : (lane == 1 ? aR1 : aR2)) + bg;
            rv = fminf(fmaxf(rv, 0.f), 1.f);
            out_rgb[r * 3 + lane] = rv;
        }
        if (lane < 20) {
            float sv = aS0 * wscs[lane] + aS1 * wscs[20 + lane] + aS2 * wscs[40 + lane] +
                       aSw * bsmS[lane];
            out_sem[r * 20 + lane] = sv;
        }
        if (lane < 16) {
            float iv = aS0 * Wi[lane] + aS1 * Wi[16 + lane] + aS2 * Wi[32 + lane];
            out_inst[r * 16 + lane] = iv;
        }
        if (lane == 0) {
            out_dep[r] = aD;
            wsdist[r] = aLu * (1.f / 3.f) + 2.f * aLb;
        }
    }
}

__global__ void reduce_dist_kernel(const float* __restrict__ ws, float* __restrict__ out) {
    __shared__ float sm[256];
    int t = threadIdx.x;
    float a = 0.f;
    const float4* w4 = (const float4*)ws;
    for (int i = t; i < NRAYS / 4; i += 256) {
        float4 v = w4[i];
        a += (v.x + v.y) + (v.z + v.w);
    }
    sm[t] = a;
    __syncthreads();
    for (int st = 128; st > 0; st >>= 1) {
        if (t < st) sm[t] += sm[t + st];
        __syncthreads();
    }
    if (t == 0) out[0] = sm[0] * (1.f / (float)NRAYS);
}

extern "C" void kernel_launch(void* const* d_in, const int* in_sizes, int n_in,
                              void* d_out, int out_size, void* d_ws, size_t ws_size,
                              hipStream_t stream) {
    const float* rays = (const float*)d_in[0];
    const float* Wd1  = (const float*)d_in[1];
    const float* bd1  = (const float*)d_in[2];
    const float* Wd2  = (const float*)d_in[3];
    const float* bd2  = (const float*)d_in[4];
    const float* Wapp = (const float*)d_in[5];
    const float* Wa1  = (const float*)d_in[6];
    const float* ba1  = (const float*)d_in[7];
    const float* Wa2  = (const float*)d_in[8];
    const float* ba2  = (const float*)d_in[9];
    const float* Wsf  = (const float*)d_in[10];
    const float* Wsm  = (const float*)d_in[11];
    const float* bsm  = (const float*)d_in[12];
    const float* Wi   = (const float*)d_in[13];
    const int* wb     = (const int*)d_in[15];

    float* out = (float*)d_out;
    float* wsd = (float*)d_ws;   // 8192 f32 per-ray dist values

    render_kernel<<<NBLK, 256, 0, stream>>>(rays, Wd1, bd1, Wd2, bd2, Wapp, Wa1, ba1,
                                            Wa2, ba2, Wsf, Wsm, bsm, Wi, wb, out, wsd);
    reduce_dist_kernel<<<1, 256, 0, stream>>>(wsd, out + 327680);
}

// Round 18
// 32.562 us; speedup vs baseline: 1.2525x; 1.0530x over previous
//
#include <hip/hip_runtime.h>

#define NRAYS 8192
#define NSAMP 173
#define LASTI 172
#define NBLK  (NRAYS / 4)

__device__ __forceinline__ float RL(float x, int u) {
    return __int_as_float(__builtin_amdgcn_readlane(__float_as_int(x), u));
}

template <int CTRL, int RM, bool BC>
__device__ __forceinline__ float updpp(float old, float x) {
    return __int_as_float(__builtin_amdgcn_update_dpp(
        __float_as_int(old), __float_as_int(x), CTRL, RM, 0xf, BC));
}

// wave64 inclusive add-scan (DPP)
__device__ __forceinline__ float scan_add64(float x) {
    x += updpp<0x111, 0xf, true>(0.f, x);
    x += updpp<0x112, 0xf, true>(0.f, x);
    x += updpp<0x114, 0xf, true>(0.f, x);
    x += updpp<0x118, 0xf, true>(0.f, x);
    x += updpp<0x142, 0xa, true>(0.f, x);
    x += updpp<0x143, 0xc, true>(0.f, x);
    return x;
}

// wave64 inclusive mul-scan (DPP)
__device__ __forceinline__ float scan_mul64(float x) {
    x *= updpp<0x111, 0xf, false>(1.f, x);
    x *= updpp<0x112, 0xf, false>(1.f, x);
    x *= updpp<0x114, 0xf, false>(1.f, x);
    x *= updpp<0x118, 0xf, false>(1.f, x);
    x *= updpp<0x142, 0xa, false>(1.f, x);
    x *= updpp<0x143, 0xc, false>(1.f, x);
    return x;
}

__device__ __forceinline__ float wave_sum64(float v) {
    return RL(scan_add64(v), 63);
}

__device__ __forceinline__ float softplus_f(float x) {
    if (x > 15.f) return x;
    return __logf(1.f + __expf(x));
}
__device__ __forceinline__ float sigmoid_f(float x) {
    return 1.f / (1.f + __expf(-x));
}

#define RMASK " row_mask:0xf bank_mask:0xf"

// one density unit 16*S+N: weights broadcast by DPP folded into fmac (no memory op)
#define DEN1(S, N)                                                                    \
    do {                                                                              \
        float t_;                                                                     \
        asm("v_mov_b32_dpp %[t], %[qw] row_newbcast:" #N RMASK "\n\t"                 \
            "v_fmac_f32_dpp %[t], %[qx], %[x0] row_newbcast:" #N RMASK "\n\t"         \
            "v_fmac_f32_dpp %[t], %[qy], %[x1] row_newbcast:" #N RMASK "\n\t"         \
            "v_fmac_f32_dpp %[t], %[qz], %[x2] row_newbcast:" #N RMASK "\n\t"         \
            "v_max_f32 %[t], 0, %[t]\n\t"                                             \
            "v_fmac_f32_dpp %[sp], %[w2], %[t] row_newbcast:" #N RMASK                \
            : [t] "=&v"(t_), [sp] "+v"(sps##S)                                        \
            : [qw] "v"(qw[S]), [qx] "v"(qx[S]), [qy] "v"(qy[S]), [qz] "v"(qz[S]),     \
              [w2] "v"(w2[S]), [x0] "v"(xn0), [x1] "v"(xn1), [x2] "v"(xn2));          \
    } while (0)

// 4 sets at same N: independent accumulator chains -> 4-way ILP
#define DEN4(N) DEN1(0, N); DEN1(1, N); DEN1(2, N); DEN1(3, N)

// one appearance unit 16*S+N, per-set c accumulators
#define APP1(S, N)                                                                    \
    do {                                                                              \
        float t_;                                                                     \
        asm("v_mov_b32_dpp %[t], %[dcv] row_newbcast:" #N RMASK "\n\t"                \
            "v_fmac_f32_dpp %[t], %[a0], %[x0] row_newbcast:" #N RMASK "\n\t"         \
            "v_fmac_f32_dpp %[t], %[a1], %[x1] row_newbcast:" #N RMASK "\n\t"         \
            "v_fmac_f32_dpp %[t], %[a2], %[x2] row_newbcast:" #N RMASK "\n\t"         \
            "v_max_f32 %[t], 0, %[t]\n\t"                                             \
            "v_fmac_f32_dpp %[c0], %[b0], %[t] row_newbcast:" #N RMASK "\n\t"         \
            "v_fmac_f32_dpp %[c1], %[b1], %[t] row_newbcast:" #N RMASK "\n\t"         \
            "v_fmac_f32_dpp %[c2], %[b2], %[t] row_newbcast:" #N RMASK                \
            : [t] "=&v"(t_), [c0] "+v"(c0##S), [c1] "+v"(c1##S), [c2] "+v"(c2##S)     \
            : [dcv] "v"(dc[S]), [a0] "v"(a0r[S]), [a1] "v"(a1r[S]), [a2] "v"(a2r[S]), \
              [b0] "v"(b0r[S]), [b1] "v"(b1r[S]), [b2] "v"(b2r[S]),                   \
              [x0] "v"(xn0), [x1] "v"(xn1), [x2] "v"(xn2));                           \
    } while (0)

#define APP4(N) APP1(0, N); APP1(1, N); APP1(2, N); APP1(3, N)

__launch_bounds__(256, 4)
__global__ void render_kernel(
    const float* __restrict__ rays,
    const float* __restrict__ Wd1, const float* __restrict__ bd1,
    const float* __restrict__ Wd2, const float* __restrict__ bd2,
    const float* __restrict__ Wapp, const float* __restrict__ Wa1,
    const float* __restrict__ ba1, const float* __restrict__ Wa2,
    const float* __restrict__ ba2, const float* __restrict__ Wsf,
    const float* __restrict__ Wsm, const float* __restrict__ bsm,
    const float* __restrict__ Wi,
    const int* __restrict__ whitebg_p,
    float* __restrict__ out,
    float* __restrict__ wsdist)
{
    // LDS used ONLY for the cooperative fold; main loops are register/DPP
    __shared__ float4 qd4[64];   // Wd1 cols + bd1
    __shared__ float  wd2s[64];  // Wd2
    __shared__ float4 apAs[64];  // (wac0, wac1, wac2, Wa2[u][0]);  wac = Wapp @ Wa1[:27]
    __shared__ float2 apBs[64];  // (Wa2[u][1], Wa2[u][2])
    __shared__ float  wscs[60];  // (Wsf @ Wsm)[m*20+s]
    __shared__ float  bsmS[20];

    const int t = threadIdx.x;
    const int wid = t >> 6, lane = t & 63;
    const int k = lane & 15;   // unit-within-set, replicated per 16-lane DPP row
    const int r = blockIdx.x * 4 + wid;

    // ---- preamble: cooperative fold (same as R13) ----
    if (t < 64) {
        qd4[t] = make_float4(Wd1[t], Wd1[64 + t], Wd1[128 + t], bd1[t]);
        wd2s[t] = Wd2[t];
    } else if (t < 128) {
        int u = t - 64;
        apBs[u] = make_float2(Wa2[3 * u + 1], Wa2[3 * u + 2]);
    } else if (t < 192) {
        int u = t - 128;
        float s0 = 0.f, s1 = 0.f, s2 = 0.f;
        for (int j = 0; j < 27; ++j) {
            float w = Wa1[j * 64 + u];
            s0 = fmaf(Wapp[j], w, s0);
            s1 = fmaf(Wapp[27 + j], w, s1);
            s2 = fmaf(Wapp[54 + j], w, s2);
        }
        apAs[u] = make_float4(s0, s1, s2, Wa2[3 * u]);
    } else {
        for (int job = t - 192; job < 80; job += 64) {
            if (job < 60) {
                int m = job / 20, s = job % 20;
                float a = 0.f;
                for (int kk = 0; kk < 32; ++kk) a = fmaf(Wsf[m * 32 + kk], Wsm[kk * 20 + s], a);
                wscs[job] = a;
            } else {
                bsmS[job - 60] = bsm[job - 60];
            }
        }
    }

    // ray (wave-uniform)
    const float o0 = rays[r * 6 + 0], o1 = rays[r * 6 + 1], o2 = rays[r * 6 + 2];
    const float d0 = rays[r * 6 + 3], d1 = rays[r * 6 + 4], d2 = rays[r * 6 + 5];

    // t_min -- replicate numpy f32 rounding exactly (knife-edge: sample 0 on box face)
    float tm;
    {
        float v0 = (d0 == 0.f) ? 1e-6f : d0;
        float v1 = (d1 == 0.f) ? 1e-6f : d1;
        float v2 = (d2 == 0.f) ? 1e-6f : d2;
        float a0 = __fdiv_rn(__fsub_rn(1.5f, o0), v0), b0 = __fdiv_rn(__fsub_rn(-1.5f, o0), v0);
        float a1 = __fdiv_rn(__fsub_rn(1.5f, o1), v1), b1 = __fdiv_rn(__fsub_rn(-1.5f, o1), v1);
        float a2 = __fdiv_rn(__fsub_rn(1.5f, o2), v2), b2 = __fdiv_rn(__fsub_rn(-1.5f, o2), v2);
        float m0 = fminf(a0, b0), m1 = fminf(a1, b1), m2 = fminf(a2, b2);
        tm = fmaxf(fmaxf(m0, m1), m2);
        tm = fminf(fmaxf(tm, 0.05f), 6.0f);
    }

    const float bd2c = bd2[0];
    const float ba2c0 = ba2[0], ba2c1 = ba2[1], ba2c2 = ba2[2];

    __syncthreads();

    // ---- weights into registers, row-replicated: lane holds units 16*S + (lane&15) ----
    float qx[4], qy[4], qz[4], qw[4], w2[4];
    float dc[4], a0r[4], a1r[4], a2r[4], b0r[4], b1r[4], b2r[4];
#pragma unroll
    for (int s = 0; s < 4; ++s) {
        int idx = 16 * s + k;
        float4 q = qd4[idx];
        qx[s] = q.x; qy[s] = q.y; qz[s] = q.z; qw[s] = q.w;
        w2[s] = wd2s[idx];
        float4 A = apAs[idx];
        a0r[s] = A.x; a1r[s] = A.y; a2r[s] = A.z; b0r[s] = A.w;
        float2 B = apBs[idx];
        b1r[s] = B.x; b2r[s] = B.y;
        float b = ba1[idx];
        b = fmaf(d0, Wa1[27 * 64 + idx], b);
        b = fmaf(d1, Wa1[28 * 64 + idx], b);
        b = fmaf(d2, Wa1[29 * 64 + idx], b);
        dc[s] = b;
    }

    const float STEPF = (float)(3.0 / 299.001 * 3.0);
    const float zlast2 = __fadd_rn(tm, __fmul_rn(171.f, STEPF));

    float aR0 = 0.f, aR1 = 0.f, aR2 = 0.f;
    float aS0 = 0.f, aS1 = 0.f, aS2 = 0.f;
    float aSw = 0.f;
    float aD = 0.f, aLu = 0.f, aLb = 0.f;
    float Tc = 1.f, Wcar = 0.f, WMc = 0.f;

    // ---- 3 chunks of 64 samples; wave-uniform early exit ----
    for (int c = 0; c < 3; ++c) {
        int i = (c << 6) + lane;
        bool valid = i < NSAMP;
        float z = __fadd_rn(tm, __fmul_rn((float)i, STEPF));
        float x0 = __fadd_rn(o0, __fmul_rn(d0, z));
        float x1 = __fadd_rn(o1, __fmul_rn(d1, z));
        float x2 = __fadd_rn(o2, __fmul_rn(d2, z));
        bool inbox = valid && (x0 >= -1.5f) && (x0 <= 1.5f) && (x1 >= -1.5f) && (x1 <= 1.5f) &&
                     (x2 >= -1.5f) && (x2 <= 1.5f);
        if (__ballot(inbox) == 0ull) break;

        float xn0 = x0 * (2.f / 3.f), xn1 = x1 * (2.f / 3.f), xn2 = x2 * (2.f / 3.f);

        // density MLP: DPP-broadcast weights, zero memory ops, 4 independent chains
        float sps0 = bd2c, sps1 = 0.f, sps2 = 0.f, sps3 = 0.f;
        DEN4(0);  DEN4(1);  DEN4(2);  DEN4(3);
        DEN4(4);  DEN4(5);  DEN4(6);  DEN4(7);
        DEN4(8);  DEN4(9);  DEN4(10); DEN4(11);
        DEN4(12); DEN4(13); DEN4(14); DEN4(15);
        float spv = (sps0 + sps1) + (sps2 + sps3);
        float sigma = inbox ? softplus_f(spv) : 0.f;

        float znext = __fadd_rn(tm, __fmul_rn((float)(i + 1), STEPF));
        float dist = (i < LASTI) ? __fsub_rn(znext, z) : 0.f;
        float alpha = 1.f - __expf(-sigma * dist * 25.f);
        float f = 1.f - alpha + 1e-10f;

        // DPP product scan
        float p = scan_mul64(f);
        float pex = updpp<0x138, 0xf, false>(1.f, p);
        float T = Tc * pex;
        float w = alpha * T;

        float mid = (i < LASTI) ? 0.5f * __fadd_rn(z, znext) : zlast2;
        float wm = w * mid;

        // DPP sum scans
        float sw = scan_add64(w);
        float swm = scan_add64(wm);
        float wex = updpp<0x138, 0xf, true>(0.f, sw);
        float wmex = updpp<0x138, 0xf, true>(0.f, swm);

        aLb += wm * (Wcar + wex) - w * (WMc + wmex);
        aLu = fmaf(dist * w, w, aLu);
        aD = fmaf(w, z, aD);

        Tc *= RL(p, 63);
        Wcar += RL(sw, 63);
        WMc += RL(swm, 63);

        // appearance (only where w > W_THRES): DPP-broadcast, 12 accumulators
        float wapp = (w > 1e-4f) ? w : 0.f;
        if (__ballot(wapp > 0.f) != 0ull) {
            float c00 = 0.f, c01 = 0.f, c02 = 0.f, c03 = 0.f;
            float c10 = 0.f, c11 = 0.f, c12 = 0.f, c13 = 0.f;
            float c20 = 0.f, c21 = 0.f, c22 = 0.f, c23 = 0.f;
            APP4(0);  APP4(1);  APP4(2);  APP4(3);
            APP4(4);  APP4(5);  APP4(6);  APP4(7);
            APP4(8);  APP4(9);  APP4(10); APP4(11);
            APP4(12); APP4(13); APP4(14); APP4(15);
            float c0v = (c00 + c01) + (c02 + c03);
            float c1v = (c10 + c11) + (c12 + c13);
            float c2v = (c20 + c21) + (c22 + c23);
            aR0 = fmaf(wapp, sigmoid_f(c0v + ba2c0), aR0);
            aR1 = fmaf(wapp, sigmoid_f(c1v + ba2c1), aR1);
            aR2 = fmaf(wapp, sigmoid_f(c2v + ba2c2), aR2);
            aS0 = fmaf(wapp, xn0, aS0);
            aS1 = fmaf(wapp, xn1, aS1);
            aS2 = fmaf(wapp, xn2, aS2);
            aSw += wapp;
        }

        if (Tc < 1e-8f) break;  // all later weights < 1e-8 << W_THRES
    }

    // wave reductions (DPP scan + readlane)
    aR0 = wave_sum64(aR0); aR1 = wave_sum64(aR1); aR2 = wave_sum64(aR2);
    aS0 = wave_sum64(aS0); aS1 = wave_sum64(aS1); aS2 = wave_sum64(aS2);
    aSw = wave_sum64(aSw);
    aD = wave_sum64(aD);
    aLu = wave_sum64(aLu);
    aLb = wave_sum64(aLb);

    float opac = Wcar;
    int wb = *whitebg_p;
    float bg = wb ? (1.f - opac) : 0.f;

    float* out_rgb = out;
    float* out_sem = out + 24576;
    float* out_inst = out + 188416;
    float* out_dep = out + 319488;

    if (lane < 3) {
        float rv = (lane == 0 ? aR0 : (lane == 1 ? aR1 : aR2)) + bg;
        rv = fminf(fmaxf(rv, 0.f), 1.f);
        out_rgb[r * 3 + lane] = rv;
    }
    if (lane < 20) {
        float sv = aS0 * wscs[lane] + aS1 * wscs[20 + lane] + aS2 * wscs[40 + lane] +
                   aSw * bsmS[lane];
        out_sem[r * 20 + lane] = sv;
    }
    if (lane < 16) {
        float iv = aS0 * Wi[lane] + aS1 * Wi[16 + lane] + aS2 * Wi[32 + lane];
        out_inst[r * 16 + lane] = iv;
    }
    if (lane == 0) {
        out_dep[r] = aD;
        wsdist[r] = aLu * (1.f / 3.f) + 2.f * aLb;
    }
}

__global__ void reduce_dist_kernel(const float* __restrict__ ws, float* __restrict__ out) {
    __shared__ float sm[256];
    int t = threadIdx.x;
    float a = 0.f;
    const float4* w4 = (const float4*)ws;
    for (int i = t; i < NRAYS / 4; i += 256) {
        float4 v = w4[i];
        a += (v.x + v.y) + (v.z + v.w);
    }
    sm[t] = a;
    __syncthreads();
    for (int st = 128; st > 0; st >>= 1) {
        if (t < st) sm[t] += sm[t + st];
        __syncthreads();
    }
    if (t == 0) out[0] = sm[0] * (1.f / (float)NRAYS);
}

extern "C" void kernel_launch(void* const* d_in, const int* in_sizes, int n_in,
                              void* d_out, int out_size, void* d_ws, size_t ws_size,
                              hipStream_t stream) {
    const float* rays = (const float*)d_in[0];
    const float* Wd1  = (const float*)d_in[1];
    const float* bd1  = (const float*)d_in[2];
    const float* Wd2  = (const float*)d_in[3];
    const float* bd2  = (const float*)d_in[4];
    const float* Wapp = (const float*)d_in[5];
    const float* Wa1  = (const float*)d_in[6];
    const float* ba1  = (const float*)d_in[7];
    const float* Wa2  = (const float*)d_in[8];
    const float* ba2  = (const float*)d_in[9];
    const float* Wsf  = (const float*)d_in[10];
    const float* Wsm  = (const float*)d_in[11];
    const float* bsm  = (const float*)d_in[12];
    const float* Wi   = (const float*)d_in[13];
    const int* wb     = (const int*)d_in[15];

    float* out = (float*)d_out;
    float* wsd = (float*)d_ws;   // 8192 f32 per-ray dist values

    render_kernel<<<NBLK, 256, 0, stream>>>(rays, Wd1, bd1, Wd2, bd2, Wapp, Wa1, ba1,
                                            Wa2, ba2, Wsf, Wsm, bsm, Wi, wb, out, wsd);
    reduce_dist_kernel<<<1, 256, 0, stream>>>(wsd, out + 327680);
}

// Round 19
// 29.453 us; speedup vs baseline: 1.3847x; 1.1056x over previous
//
#include <hip/hip_runtime.h>

#define NRAYS 8192
#define NSAMP 173
#define LASTI 172
#define NBLK  (NRAYS / 4)

__device__ __forceinline__ float RL(float x, int u) {
    return __int_as_float(__builtin_amdgcn_readlane(__float_as_int(x), u));
}

template <int CTRL, int RM, bool BC>
__device__ __forceinline__ float updpp(float old, float x) {
    return __int_as_float(__builtin_amdgcn_update_dpp(
        __float_as_int(old), __float_as_int(x), CTRL, RM, 0xf, BC));
}

// wave64 inclusive add-scan (DPP)
__device__ __forceinline__ float scan_add64(float x) {
    x += updpp<0x111, 0xf, true>(0.f, x);
    x += updpp<0x112, 0xf, true>(0.f, x);
    x += updpp<0x114, 0xf, true>(0.f, x);
    x += updpp<0x118, 0xf, true>(0.f, x);
    x += updpp<0x142, 0xa, true>(0.f, x);
    x += updpp<0x143, 0xc, true>(0.f, x);
    return x;
}

// wave64 inclusive mul-scan (DPP)
__device__ __forceinline__ float scan_mul64(float x) {
    x *= updpp<0x111, 0xf, false>(1.f, x);
    x *= updpp<0x112, 0xf, false>(1.f, x);
    x *= updpp<0x114, 0xf, false>(1.f, x);
    x *= updpp<0x118, 0xf, false>(1.f, x);
    x *= updpp<0x142, 0xa, false>(1.f, x);
    x *= updpp<0x143, 0xc, false>(1.f, x);
    return x;
}

__device__ __forceinline__ float wave_sum64(float v) {
    return RL(scan_add64(v), 63);
}

__device__ __forceinline__ float softplus_f(float x) {
    if (x > 15.f) return x;
    return __logf(1.f + __expf(x));
}
__device__ __forceinline__ float sigmoid_f(float x) {
    return 1.f / (1.f + __expf(-x));
}

#define RMASK " row_mask:0xf bank_mask:0xf"

// one appearance unit 16*S+N: weights broadcast by DPP folded into fmac (VALU pipe)
#define APP1(S, N)                                                                    \
    do {                                                                              \
        float t_;                                                                     \
        asm("v_mov_b32_dpp %[t], %[dcv] row_newbcast:" #N RMASK "\n\t"                \
            "v_fmac_f32_dpp %[t], %[a0], %[x0] row_newbcast:" #N RMASK "\n\t"         \
            "v_fmac_f32_dpp %[t], %[a1], %[x1] row_newbcast:" #N RMASK "\n\t"         \
            "v_fmac_f32_dpp %[t], %[a2], %[x2] row_newbcast:" #N RMASK "\n\t"         \
            "v_max_f32 %[t], 0, %[t]\n\t"                                             \
            "v_fmac_f32_dpp %[c0], %[b0], %[t] row_newbcast:" #N RMASK "\n\t"         \
            "v_fmac_f32_dpp %[c1], %[b1], %[t] row_newbcast:" #N RMASK "\n\t"         \
            "v_fmac_f32_dpp %[c2], %[b2], %[t] row_newbcast:" #N RMASK                \
            : [t] "=&v"(t_), [c0] "+v"(c0##S), [c1] "+v"(c1##S), [c2] "+v"(c2##S)     \
            : [dcv] "v"(dc[S]), [a0] "v"(a0r[S]), [a1] "v"(a1r[S]), [a2] "v"(a2r[S]), \
              [b0] "v"(b0r[S]), [b1] "v"(b1r[S]), [b2] "v"(b2r[S]),                   \
              [x0] "v"(xn0), [x1] "v"(xn1), [x2] "v"(xn2));                           \
    } while (0)

#define APP4(N) APP1(0, N); APP1(1, N); APP1(2, N); APP1(3, N)

__launch_bounds__(256, 4)
__global__ void render_kernel(
    const float* __restrict__ rays,
    const float* __restrict__ Wd1, const float* __restrict__ bd1,
    const float* __restrict__ Wd2, const float* __restrict__ bd2,
    const float* __restrict__ Wapp, const float* __restrict__ Wa1,
    const float* __restrict__ ba1, const float* __restrict__ Wa2,
    const float* __restrict__ ba2, const float* __restrict__ Wsf,
    const float* __restrict__ Wsm, const float* __restrict__ bsm,
    const float* __restrict__ Wi,
    const int* __restrict__ whitebg_p,
    float* __restrict__ out,
    float* __restrict__ wsdist)
{
    // density weights stay in LDS (LDS pipe); appearance weights go to registers
    // broadcast via DPP-fmac (VALU pipe) -- the two loops ride different pipes.
    __shared__ float4 qd4[64];   // Wd1 cols + bd1
    __shared__ float  wd2s[64];  // Wd2
    __shared__ float4 apAs[64];  // (wac0, wac1, wac2, Wa2[u][0]);  wac = Wapp @ Wa1[:27]
    __shared__ float2 apBs[64];  // (Wa2[u][1], Wa2[u][2])
    __shared__ float  wscs[60];  // (Wsf @ Wsm)[m*20+s]
    __shared__ float  bsmS[20];

    const int t = threadIdx.x;
    const int wid = t >> 6, lane = t & 63;
    const int k = lane & 15;   // unit-within-set, replicated per 16-lane DPP row
    const int r = blockIdx.x * 4 + wid;

    // ---- preamble: cooperative fold (same as R13) ----
    if (t < 64) {
        qd4[t] = make_float4(Wd1[t], Wd1[64 + t], Wd1[128 + t], bd1[t]);
        wd2s[t] = Wd2[t];
    } else if (t < 128) {
        int u = t - 64;
        apBs[u] = make_float2(Wa2[3 * u + 1], Wa2[3 * u + 2]);
    } else if (t < 192) {
        int u = t - 128;
        float s0 = 0.f, s1 = 0.f, s2 = 0.f;
        for (int j = 0; j < 27; ++j) {
            float w = Wa1[j * 64 + u];
            s0 = fmaf(Wapp[j], w, s0);
            s1 = fmaf(Wapp[27 + j], w, s1);
            s2 = fmaf(Wapp[54 + j], w, s2);
        }
        apAs[u] = make_float4(s0, s1, s2, Wa2[3 * u]);
    } else {
        for (int job = t - 192; job < 80; job += 64) {
            if (job < 60) {
                int m = job / 20, s = job % 20;
                float a = 0.f;
                for (int kk = 0; kk < 32; ++kk) a = fmaf(Wsf[m * 32 + kk], Wsm[kk * 20 + s], a);
                wscs[job] = a;
            } else {
                bsmS[job - 60] = bsm[job - 60];
            }
        }
    }

    // ray (wave-uniform)
    const float o0 = rays[r * 6 + 0], o1 = rays[r * 6 + 1], o2 = rays[r * 6 + 2];
    const float d0 = rays[r * 6 + 3], d1 = rays[r * 6 + 4], d2 = rays[r * 6 + 5];

    // t_min -- replicate numpy f32 rounding exactly (knife-edge: sample 0 on box face)
    float tm;
    {
        float v0 = (d0 == 0.f) ? 1e-6f : d0;
        float v1 = (d1 == 0.f) ? 1e-6f : d1;
        float v2 = (d2 == 0.f) ? 1e-6f : d2;
        float a0 = __fdiv_rn(__fsub_rn(1.5f, o0), v0), b0 = __fdiv_rn(__fsub_rn(-1.5f, o0), v0);
        float a1 = __fdiv_rn(__fsub_rn(1.5f, o1), v1), b1 = __fdiv_rn(__fsub_rn(-1.5f, o1), v1);
        float a2 = __fdiv_rn(__fsub_rn(1.5f, o2), v2), b2 = __fdiv_rn(__fsub_rn(-1.5f, o2), v2);
        float m0 = fminf(a0, b0), m1 = fminf(a1, b1), m2 = fminf(a2, b2);
        tm = fmaxf(fmaxf(m0, m1), m2);
        tm = fminf(fmaxf(tm, 0.05f), 6.0f);
    }

    const float bd2c = bd2[0];
    const float ba2c0 = ba2[0], ba2c1 = ba2[1], ba2c2 = ba2[2];

    __syncthreads();

    // ---- appearance weights into registers, row-replicated (units 16*S + lane&15) ----
    float dc[4], a0r[4], a1r[4], a2r[4], b0r[4], b1r[4], b2r[4];
#pragma unroll
    for (int s = 0; s < 4; ++s) {
        int idx = 16 * s + k;
        float4 A = apAs[idx];
        a0r[s] = A.x; a1r[s] = A.y; a2r[s] = A.z; b0r[s] = A.w;
        float2 B = apBs[idx];
        b1r[s] = B.x; b2r[s] = B.y;
        float b = ba1[idx];
        b = fmaf(d0, Wa1[27 * 64 + idx], b);
        b = fmaf(d1, Wa1[28 * 64 + idx], b);
        b = fmaf(d2, Wa1[29 * 64 + idx], b);
        dc[s] = b;
    }

    const float STEPF = (float)(3.0 / 299.001 * 3.0);
    const float zlast2 = __fadd_rn(tm, __fmul_rn(171.f, STEPF));

    float aR0 = 0.f, aR1 = 0.f, aR2 = 0.f;
    float aS0 = 0.f, aS1 = 0.f, aS2 = 0.f;
    float aSw = 0.f;
    float aD = 0.f, aLu = 0.f, aLb = 0.f;
    float Tc = 1.f, Wcar = 0.f, WMc = 0.f;

    // ---- 3 chunks of 64 samples; wave-uniform inbox early exit ----
    for (int c = 0; c < 3; ++c) {
        int i = (c << 6) + lane;
        bool valid = i < NSAMP;
        float z = __fadd_rn(tm, __fmul_rn((float)i, STEPF));
        float x0 = __fadd_rn(o0, __fmul_rn(d0, z));
        float x1 = __fadd_rn(o1, __fmul_rn(d1, z));
        float x2 = __fadd_rn(o2, __fmul_rn(d2, z));
        bool inbox = valid && (x0 >= -1.5f) && (x0 <= 1.5f) && (x1 >= -1.5f) && (x1 <= 1.5f) &&
                     (x2 >= -1.5f) && (x2 <= 1.5f);
        if (__ballot(inbox) == 0ull) break;  // in-box span is contiguous from sample 0

        float xn0 = x0 * (2.f / 3.f), xn1 = x1 * (2.f / 3.f), xn2 = x2 * (2.f / 3.f);

        // density MLP (LDS broadcast weights -- LDS pipe)
        float sp = bd2c;
#pragma unroll 8
        for (int u = 0; u < 64; ++u) {
            float4 q = qd4[u];
            float h = fmaf(xn0, q.x, fmaf(xn1, q.y, fmaf(xn2, q.z, q.w)));
            sp = fmaf(fmaxf(h, 0.f), wd2s[u], sp);
        }
        float sigma = inbox ? softplus_f(sp) : 0.f;

        float znext = __fadd_rn(tm, __fmul_rn((float)(i + 1), STEPF));
        float dist = (i < LASTI) ? __fsub_rn(znext, z) : 0.f;
        float alpha = 1.f - __expf(-sigma * dist * 25.f);
        float f = 1.f - alpha + 1e-10f;

        // DPP product scan
        float p = scan_mul64(f);
        float pex = updpp<0x138, 0xf, false>(1.f, p);  // wave_shr1, lane0 -> 1
        float T = Tc * pex;
        float w = alpha * T;

        float mid = (i < LASTI) ? 0.5f * __fadd_rn(z, znext) : zlast2;
        float wm = w * mid;

        // DPP sum scans
        float sw = scan_add64(w);
        float swm = scan_add64(wm);
        float wex = updpp<0x138, 0xf, true>(0.f, sw);
        float wmex = updpp<0x138, 0xf, true>(0.f, swm);

        aLb += wm * (Wcar + wex) - w * (WMc + wmex);
        aLu = fmaf(dist * w, w, aLu);
        aD = fmaf(w, z, aD);

        Tc *= RL(p, 63);
        Wcar += RL(sw, 63);
        WMc += RL(swm, 63);

        // appearance (only where w > W_THRES): DPP-broadcast registers (VALU pipe)
        float wapp = (w > 1e-4f) ? w : 0.f;
        if (__ballot(wapp > 0.f) != 0ull) {
            float c00 = 0.f, c01 = 0.f, c02 = 0.f, c03 = 0.f;
            float c10 = 0.f, c11 = 0.f, c12 = 0.f, c13 = 0.f;
            float c20 = 0.f, c21 = 0.f, c22 = 0.f, c23 = 0.f;
            APP4(0);  APP4(1);  APP4(2);  APP4(3);
            APP4(4);  APP4(5);  APP4(6);  APP4(7);
            APP4(8);  APP4(9);  APP4(10); APP4(11);
            APP4(12); APP4(13); APP4(14); APP4(15);
            float c0v = (c00 + c01) + (c02 + c03);
            float c1v = (c10 + c11) + (c12 + c13);
            float c2v = (c20 + c21) + (c22 + c23);
            aR0 = fmaf(wapp, sigmoid_f(c0v + ba2c0), aR0);
            aR1 = fmaf(wapp, sigmoid_f(c1v + ba2c1), aR1);
            aR2 = fmaf(wapp, sigmoid_f(c2v + ba2c2), aR2);
            aS0 = fmaf(wapp, xn0, aS0);
            aS1 = fmaf(wapp, xn1, aS1);
            aS2 = fmaf(wapp, xn2, aS2);
            aSw += wapp;
        }

        if (Tc < 1e-8f) break;
    }

    // wave reductions (DPP scan + readlane)
    aR0 = wave_sum64(aR0); aR1 = wave_sum64(aR1); aR2 = wave_sum64(aR2);
    aS0 = wave_sum64(aS0); aS1 = wave_sum64(aS1); aS2 = wave_sum64(aS2);
    aSw = wave_sum64(aSw);
    aD = wave_sum64(aD);
    aLu = wave_sum64(aLu);
    aLb = wave_sum64(aLb);

    float opac = Wcar;
    int wb = *whitebg_p;
    float bg = wb ? (1.f - opac) : 0.f;

    float* out_rgb = out;
    float* out_sem = out + 24576;
    float* out_inst = out + 188416;
    float* out_dep = out + 319488;

    if (lane < 3) {
        float rv = (lane == 0 ? aR0 : (lane == 1 ? aR1 : aR2)) + bg;
        rv = fminf(fmaxf(rv, 0.f), 1.f);
        out_rgb[r * 3 + lane] = rv;
    }
    if (lane < 20) {
        float sv = aS0 * wscs[lane] + aS1 * wscs[20 + lane] + aS2 * wscs[40 + lane] +
                   aSw * bsmS[lane];
        out_sem[r * 20 + lane] = sv;
    }
    if (lane < 16) {
        float iv = aS0 * Wi[lane] + aS1 * Wi[16 + lane] + aS2 * Wi[32 + lane];
        out_inst[r * 16 + lane] = iv;
    }
    if (lane == 0) {
        out_dep[r] = aD;
        wsdist[r] = aLu * (1.f / 3.f) + 2.f * aLb;
    }
}

__global__ void reduce_dist_kernel(const float* __restrict__ ws, float* __restrict__ out) {
    __shared__ float sm[256];
    int t = threadIdx.x;
    float a = 0.f;
    const float4* w4 = (const float4*)ws;
    for (int i = t; i < NRAYS / 4; i += 256) {
        float4 v = w4[i];
        a += (v.x + v.y) + (v.z + v.w);
    }
    sm[t] = a;
    __syncthreads();
    for (int st = 128; st > 0; st >>= 1) {
        if (t < st) sm[t] += sm[t + st];
        __syncthreads();
    }
    if (t == 0) out[0] = sm[0] * (1.f / (float)NRAYS);
}

extern "C" void kernel_launch(void* const* d_in, const int* in_sizes, int n_in,
                              void* d_out, int out_size, void* d_ws, size_t ws_size,
                              hipStream_t stream) {
    const float* rays = (const float*)d_in[0];
    const float* Wd1  = (const float*)d_in[1];
    const float* bd1  = (const float*)d_in[2];
    const float* Wd2  = (const float*)d_in[3];
    const float* bd2  = (const float*)d_in[4];
    const float* Wapp = (const float*)d_in[5];
    const float* Wa1  = (const float*)d_in[6];
    const float* ba1  = (const float*)d_in[7];
    const float* Wa2  = (const float*)d_in[8];
    const float* ba2  = (const float*)d_in[9];
    const float* Wsf  = (const float*)d_in[10];
    const float* Wsm  = (const float*)d_in[11];
    const float* bsm  = (const float*)d_in[12];
    const float* Wi   = (const float*)d_in[13];
    const int* wb     = (const int*)d_in[15];

    float* out = (float*)d_out;
    float* wsd = (float*)d_ws;   // 8192 f32 per-ray dist values

    render_kernel<<<NBLK, 256, 0, stream>>>(rays, Wd1, bd1, Wd2, bd2, Wapp, Wa1, ba1,
                                            Wa2, ba2, Wsf, Wsm, bsm, Wi, wb, out, wsd);
    reduce_dist_kernel<<<1, 256, 0, stream>>>(wsd, out + 327680);
}